// Round 1
// baseline (2168.006 us; speedup 1.0000x reference)
//
#include <hip/hip_runtime.h>
#include <cmath>

#define NN 100000
#define NE 1600000
#define NBATCH 64

__device__ __forceinline__ void atomAdd(float* p, float v) {
  unsafeAtomicAdd(p, v);
}

// ---------------- degree / dinv ----------------
__global__ __launch_bounds__(256) void k_deg(const int* __restrict__ dst, float* __restrict__ deg) {
  int e = blockIdx.x * 256 + threadIdx.x;
  if (e < NE) atomAdd(&deg[dst[e]], 1.0f);
}

__global__ __launch_bounds__(256) void k_dinv(float* __restrict__ d) {
  int i = blockIdx.x * 256 + threadIdx.x;
  if (i < NN) d[i] = rsqrtf(d[i] + 1.0f);
}

// ---------------- edge scatter (aggregation in d_in dims) ----------------
__global__ __launch_bounds__(256) void k_scatter5(const float* __restrict__ x,
    const int* __restrict__ src, const int* __restrict__ dst,
    const float* __restrict__ dinv, float* __restrict__ agg) {
  int e = blockIdx.x * 256 + threadIdx.x;
  if (e >= NE) return;
  int s = src[e], d = dst[e];
  float w = dinv[s] * dinv[d];
  const float* ip = x + (size_t)s * 5;
  float* ap = agg + (size_t)d * 5;
#pragma unroll
  for (int k = 0; k < 5; ++k) atomAdd(&ap[k], ip[k] * w);
}

template<int K, int LOG2K>
__global__ __launch_bounds__(256) void k_scatter(const float* __restrict__ in,
    const int* __restrict__ src, const int* __restrict__ dst,
    const float* __restrict__ dinv, float* __restrict__ agg) {
  unsigned gid = blockIdx.x * 256u + threadIdx.x;
  if (gid >= (unsigned)NE * (unsigned)K) return;
  int e = (int)(gid >> LOG2K);
  int k = (int)(gid & (K - 1));
  int s = src[e], d = dst[e];
  float w = dinv[s] * dinv[d];
  atomAdd(&agg[(size_t)d * K + k], in[(size_t)s * K + k] * w);
}

// ---------------- fused (agg + self-loop) @ W + bias + ReLU ----------------
// Block: 256 threads, covers RT=64 rows x all M cols. W chunk + input tile in LDS.
template<int K, int M>
__global__ __launch_bounds__(256) void k_gemm(const float* __restrict__ agg,
    const float* __restrict__ in, const float* __restrict__ dinv,
    const float* __restrict__ Wm, const float* __restrict__ bias,
    float* __restrict__ out) {
  constexpr int M4 = M / 4;
  constexpr int GROUPS = 256 / M4;
  constexpr int RR = 64 / GROUPS;
  constexpr int RT = 64;
  constexpr int KC = (K < 32) ? K : 32;
  __shared__ float in_s[RT * K];
  __shared__ float w_s[KC * M];
  const int r0 = blockIdx.x * RT;

  // stage input tile: agg[row] + in[row]*dinv[row]^2 (self-loop folded in)
  for (int idx = threadIdx.x; idx < RT * K; idx += 256) {
    int r = idx / K, k = idx - r * K;
    int row = r0 + r;
    float v = 0.f;
    if (row < NN) {
      float di = dinv[row];
      v = agg[(size_t)row * K + k] + in[(size_t)row * K + k] * (di * di);
    }
    in_s[idx] = v;
  }

  const int tx = threadIdx.x % M4;
  const int g  = threadIdx.x / M4;
  float acc[RR][4];
#pragma unroll
  for (int r = 0; r < RR; ++r) { acc[r][0] = acc[r][1] = acc[r][2] = acc[r][3] = 0.f; }

  for (int kc = 0; kc < K; kc += KC) {
    __syncthreads();
    for (int idx = threadIdx.x; idx < KC * M; idx += 256)
      w_s[idx] = Wm[kc * M + idx];
    __syncthreads();
    if constexpr ((K & 1) == 0) {
#pragma unroll
      for (int kk = 0; kk < KC; kk += 2) {
        const float4 w0 = *(const float4*)&w_s[(kk    ) * M + tx * 4];
        const float4 w1 = *(const float4*)&w_s[(kk + 1) * M + tx * 4];
#pragma unroll
        for (int r = 0; r < RR; ++r) {
          const float2 a = *(const float2*)&in_s[(g * RR + r) * K + kc + kk];
          acc[r][0] += a.x * w0.x; acc[r][1] += a.x * w0.y;
          acc[r][2] += a.x * w0.z; acc[r][3] += a.x * w0.w;
          acc[r][0] += a.y * w1.x; acc[r][1] += a.y * w1.y;
          acc[r][2] += a.y * w1.z; acc[r][3] += a.y * w1.w;
        }
      }
    } else {
#pragma unroll
      for (int kk = 0; kk < KC; ++kk) {
        const float4 w0 = *(const float4*)&w_s[kk * M + tx * 4];
#pragma unroll
        for (int r = 0; r < RR; ++r) {
          const float a = in_s[(g * RR + r) * K + kc + kk];
          acc[r][0] += a * w0.x; acc[r][1] += a * w0.y;
          acc[r][2] += a * w0.z; acc[r][3] += a * w0.w;
        }
      }
    }
  }

  const float4 bv = *(const float4*)&bias[tx * 4];
#pragma unroll
  for (int r = 0; r < RR; ++r) {
    int row = r0 + g * RR + r;
    if (row < NN) {
      float4 o;
      o.x = fmaxf(acc[r][0] + bv.x, 0.f);
      o.y = fmaxf(acc[r][1] + bv.y, 0.f);
      o.z = fmaxf(acc[r][2] + bv.z, 0.f);
      o.w = fmaxf(acc[r][3] + bv.w, 0.f);
      *(float4*)&out[(size_t)row * M + tx * 4] = o;
    }
  }
}

// ---------------- mean pool (batch is sorted) ----------------
__global__ __launch_bounds__(256) void k_pool(const float* __restrict__ h,
    const int* __restrict__ batch, float* __restrict__ pooled, float* __restrict__ cnt) {
  const int c = threadIdx.x;           // feature 0..255
  const int v0 = blockIdx.x * 128;
  if (v0 >= NN) return;
  const int vend = (v0 + 128 < NN) ? v0 + 128 : NN;
  float acc = 0.f;
  int curb = batch[v0];
  int run = 0;
  for (int v = v0; v < vend; ++v) {
    int b = batch[v];
    if (b != curb) {
      atomAdd(&pooled[curb * 256 + c], acc);
      if (c == 0) atomAdd(&cnt[curb], (float)run);
      acc = 0.f; run = 0; curb = b;
    }
    acc += h[(size_t)v * 256 + c];
    ++run;
  }
  atomAdd(&pooled[curb * 256 + c], acc);
  if (c == 0) atomAdd(&cnt[curb], (float)run);
}

// ---------------- MLP head + log_softmax ----------------
__global__ __launch_bounds__(128) void k_mlp(const float* __restrict__ pooled,
    const float* __restrict__ cnt, const float* __restrict__ w1,
    const float* __restrict__ b1, const float* __restrict__ w2,
    const float* __restrict__ b2, float* __restrict__ out) {
  __shared__ float p[256];
  __shared__ float h1[100];
  __shared__ float lo[10];
  const int b = blockIdx.x;
  const float inv = 1.0f / fmaxf(cnt[b], 1.0f);
  for (int i = threadIdx.x; i < 256; i += 128) p[i] = pooled[b * 256 + i] * inv;
  __syncthreads();
  for (int j = threadIdx.x; j < 100; j += 128) {
    float s = b1[j];
    for (int k = 0; k < 256; ++k) s += p[k] * w1[k * 100 + j];
    h1[j] = fmaxf(s, 0.f);
  }
  __syncthreads();
  if (threadIdx.x < 10) {
    int j = threadIdx.x;
    float s = b2[j];
    for (int k = 0; k < 100; ++k) s += h1[k] * w2[k * 10 + j];
    lo[j] = s;
  }
  __syncthreads();
  if (threadIdx.x == 0) {
    float m = lo[0];
    for (int j = 1; j < 10; ++j) m = fmaxf(m, lo[j]);
    float ssum = 0.f;
    for (int j = 0; j < 10; ++j) ssum += expf(lo[j] - m);
    float lse = m + logf(ssum);
    for (int j = 0; j < 10; ++j) out[b * 10 + j] = lo[j] - lse;
  }
}

extern "C" void kernel_launch(void* const* d_in, const int* in_sizes, int n_in,
                              void* d_out, int out_size, void* d_ws, size_t ws_size,
                              hipStream_t stream) {
  const float* x    = (const float*)d_in[0];
  const int*   ei   = (const int*)d_in[1];
  const int*   batch= (const int*)d_in[2];
  const float* W1 = (const float*)d_in[3];  const float* b1 = (const float*)d_in[4];
  const float* W2 = (const float*)d_in[5];  const float* b2 = (const float*)d_in[6];
  const float* W3 = (const float*)d_in[7];  const float* b3 = (const float*)d_in[8];
  const float* W4 = (const float*)d_in[9];  const float* b4 = (const float*)d_in[10];
  const float* fc1w = (const float*)d_in[11]; const float* fc1b = (const float*)d_in[12];
  const float* fc2w = (const float*)d_in[13]; const float* fc2b = (const float*)d_in[14];
  float* out = (float*)d_out;

  const int* src = ei;        // edge_index[0]
  const int* dst = ei + NE;   // edge_index[1]

  // workspace layout (floats): dinv | R(N*128) | F0(N*128) | F1(N*256) | pooled | cnt
  float* ws   = (float*)d_ws;
  float* dinv = ws;                        // NN (rounded to 100096)
  float* R    = ws + 100096;               // NN*128
  float* F0   = R  + 12800000;             // NN*128
  float* F1   = F0 + 12800000;             // NN*256
  float* pooled = F1 + 25600000;           // 64*256
  float* cnt  = pooled + 16384;            // 64

  // degree + dinv
  hipMemsetAsync(dinv, 0, NN * sizeof(float), stream);
  k_deg<<<(NE + 255) / 256, 256, 0, stream>>>(dst, dinv);
  k_dinv<<<(NN + 255) / 256, 256, 0, stream>>>(dinv);

  // layer 1: aggregate x (K=5), then GEMM 5->32
  hipMemsetAsync(R, 0, (size_t)NN * 5 * sizeof(float), stream);
  k_scatter5<<<(NE + 255) / 256, 256, 0, stream>>>(x, src, dst, dinv, R);
  k_gemm<5, 32><<<(NN + 63) / 64, 256, 0, stream>>>(R, x, dinv, W1, b1, F0);

  // layer 2: K=32 -> M=64
  hipMemsetAsync(R, 0, (size_t)NN * 32 * sizeof(float), stream);
  k_scatter<32, 5><<<(NE * 32) / 256, 256, 0, stream>>>(F0, src, dst, dinv, R);
  k_gemm<32, 64><<<(NN + 63) / 64, 256, 0, stream>>>(R, F0, dinv, W2, b2, F1);

  // layer 3: K=64 -> M=128
  hipMemsetAsync(R, 0, (size_t)NN * 64 * sizeof(float), stream);
  k_scatter<64, 6><<<(NE * 64) / 256, 256, 0, stream>>>(F1, src, dst, dinv, R);
  k_gemm<64, 128><<<(NN + 63) / 64, 256, 0, stream>>>(R, F1, dinv, W3, b3, F0);

  // layer 4: K=128 -> M=256
  hipMemsetAsync(R, 0, (size_t)NN * 128 * sizeof(float), stream);
  k_scatter<128, 7><<<(NE * 128) / 256 + 1, 256, 0, stream>>>(F0, src, dst, dinv, R);
  k_gemm<128, 256><<<(NN + 63) / 64, 256, 0, stream>>>(R, F0, dinv, W4, b4, F1);

  // mean pool + MLP head
  hipMemsetAsync(pooled, 0, (16384 + 64) * sizeof(float), stream);
  k_pool<<<(NN + 127) / 128, 256, 0, stream>>>(F1, batch, pooled, cnt);
  k_mlp<<<NBATCH, 128, 0, stream>>>(pooled, cnt, fc1w, fc1b, fc2w, fc2b, out);
}

// Round 2
// 864.379 us; speedup vs baseline: 2.5082x; 2.5082x over previous
//
#include <hip/hip_runtime.h>
#include <cmath>

#define NN 100000
#define NE 1600000
#define NBATCH 64

__device__ __forceinline__ void atomAdd(float* p, float v) {
  unsafeAtomicAdd(p, v);
}

// ---------------- degree count (int) ----------------
__global__ __launch_bounds__(256) void k_deg(const int* __restrict__ dst, int* __restrict__ cnt) {
  int e = blockIdx.x * 256 + threadIdx.x;
  if (e < NE) atomicAdd(&cnt[dst[e]], 1);
}

__global__ __launch_bounds__(256) void k_dinv(const int* __restrict__ cnt, float* __restrict__ d) {
  int i = blockIdx.x * 256 + threadIdx.x;
  if (i < NN) d[i] = rsqrtf((float)cnt[i] + 1.0f);
}

// ---------------- exclusive scan (3 kernels) ----------------
__global__ __launch_bounds__(512) void k_scan1(const int* __restrict__ cnt,
    int* __restrict__ excl, int* __restrict__ partial) {
  __shared__ int sh[512];
  int i = blockIdx.x * 512 + threadIdx.x;
  int v = (i < NN) ? cnt[i] : 0;
  sh[threadIdx.x] = v;
  __syncthreads();
  for (int off = 1; off < 512; off <<= 1) {
    int t = (threadIdx.x >= (unsigned)off) ? sh[threadIdx.x - off] : 0;
    __syncthreads();
    sh[threadIdx.x] += t;
    __syncthreads();
  }
  if (i < NN) excl[i] = sh[threadIdx.x] - v;
  if (threadIdx.x == 511) partial[blockIdx.x] = sh[511];
}

__global__ __launch_bounds__(256) void k_scan2(int* __restrict__ partial) {
  __shared__ int sh[256];
  int v = (threadIdx.x < 196) ? partial[threadIdx.x] : 0;
  sh[threadIdx.x] = v;
  __syncthreads();
  for (int off = 1; off < 256; off <<= 1) {
    int t = (threadIdx.x >= (unsigned)off) ? sh[threadIdx.x - off] : 0;
    __syncthreads();
    sh[threadIdx.x] += t;
    __syncthreads();
  }
  if (threadIdx.x < 196) partial[threadIdx.x] = sh[threadIdx.x] - v;
}

__global__ __launch_bounds__(512) void k_scan3(const int* __restrict__ excl,
    const int* __restrict__ partial, int* __restrict__ rowptr, int* __restrict__ fillpos) {
  int i = blockIdx.x * 512 + threadIdx.x;
  if (i < NN) {
    int v = excl[i] + partial[blockIdx.x];
    rowptr[i] = v;
    fillpos[i] = v;
  }
  if (i == NN) rowptr[NN] = NE;
}

__global__ __launch_bounds__(256) void k_fill(const int* __restrict__ src,
    const int* __restrict__ dst, int* __restrict__ fillpos, int* __restrict__ csrc) {
  int e = blockIdx.x * 256 + threadIdx.x;
  if (e < NE) {
    int pos = atomicAdd(&fillpos[dst[e]], 1);
    csrc[pos] = src[e];
  }
}

// ---------------- CSR gather aggregation: agg = D^-1/2 (A+I) D^-1/2 in ----------------
template<int K>
__global__ __launch_bounds__(256) void k_gather(const float* __restrict__ in,
    const int* __restrict__ rowptr, const int* __restrict__ csrc,
    const float* __restrict__ dinv, float* __restrict__ agg) {
  constexpr int TPR = K / 4;        // float4 per lane
  constexpr int RPB = 256 / TPR;
  const int r = blockIdx.x * RPB + threadIdx.x / TPR;
  const int c = (threadIdx.x % TPR) * 4;
  const float di = dinv[r];
  const float sl = di * di;
  float4 a0 = *(const float4*)(in + (size_t)r * K + c);
  a0.x *= sl; a0.y *= sl; a0.z *= sl; a0.w *= sl;
  float4 a1 = {0.f, 0.f, 0.f, 0.f};
  int e = rowptr[r];
  const int e1 = rowptr[r + 1];
  for (; e + 2 <= e1; e += 2) {
    const int s0 = csrc[e], s1 = csrc[e + 1];
    const float w0 = dinv[s0] * di, w1 = dinv[s1] * di;
    const float4 x0 = *(const float4*)(in + (size_t)s0 * K + c);
    const float4 x1 = *(const float4*)(in + (size_t)s1 * K + c);
    a0.x += x0.x * w0; a0.y += x0.y * w0; a0.z += x0.z * w0; a0.w += x0.w * w0;
    a1.x += x1.x * w1; a1.y += x1.y * w1; a1.z += x1.z * w1; a1.w += x1.w * w1;
  }
  if (e < e1) {
    const int s0 = csrc[e];
    const float w0 = dinv[s0] * di;
    const float4 x0 = *(const float4*)(in + (size_t)s0 * K + c);
    a0.x += x0.x * w0; a0.y += x0.y * w0; a0.z += x0.z * w0; a0.w += x0.w * w0;
  }
  float4 o;
  o.x = a0.x + a1.x; o.y = a0.y + a1.y; o.z = a0.z + a1.z; o.w = a0.w + a1.w;
  *(float4*)(agg + (size_t)r * K + c) = o;
}

__global__ __launch_bounds__(256) void k_gather5(const float* __restrict__ in,
    const int* __restrict__ rowptr, const int* __restrict__ csrc,
    const float* __restrict__ dinv, float* __restrict__ agg) {
  const int r = blockIdx.x * 32 + threadIdx.x / 8;
  const int k = threadIdx.x % 8;
  if (k >= 5) return;
  const float di = dinv[r];
  float acc = in[(size_t)r * 5 + k] * di * di;
  const int e1 = rowptr[r + 1];
  for (int e = rowptr[r]; e < e1; ++e) {
    const int s = csrc[e];
    acc += in[(size_t)s * 5 + k] * dinv[s] * di;
  }
  agg[(size_t)r * 5 + k] = acc;
}

// ---------------- agg @ W + bias + ReLU ----------------
template<int K, int M>
__global__ __launch_bounds__(256) void k_gemm(const float* __restrict__ agg,
    const float* __restrict__ Wm, const float* __restrict__ bias,
    float* __restrict__ out) {
  constexpr int M4 = M / 4;
  constexpr int GROUPS = 256 / M4;
  constexpr int RR = 64 / GROUPS;
  constexpr int RT = 64;
  constexpr int KC = (K < 32) ? K : 32;
  __shared__ float in_s[RT * K];
  __shared__ float w_s[KC * M];
  const int r0 = blockIdx.x * RT;

  for (int idx = threadIdx.x; idx < RT * K; idx += 256) {
    int r = idx / K, k = idx - r * K;
    int row = r0 + r;
    in_s[idx] = (row < NN) ? agg[(size_t)row * K + k] : 0.f;
  }

  const int tx = threadIdx.x % M4;
  const int g  = threadIdx.x / M4;
  float acc[RR][4];
#pragma unroll
  for (int r = 0; r < RR; ++r) { acc[r][0] = acc[r][1] = acc[r][2] = acc[r][3] = 0.f; }

  for (int kc = 0; kc < K; kc += KC) {
    __syncthreads();
    for (int idx = threadIdx.x; idx < KC * M; idx += 256)
      w_s[idx] = Wm[kc * M + idx];
    __syncthreads();
    if constexpr ((K & 1) == 0) {
#pragma unroll
      for (int kk = 0; kk < KC; kk += 2) {
        const float4 w0 = *(const float4*)&w_s[(kk    ) * M + tx * 4];
        const float4 w1 = *(const float4*)&w_s[(kk + 1) * M + tx * 4];
#pragma unroll
        for (int r = 0; r < RR; ++r) {
          const float2 a = *(const float2*)&in_s[(g * RR + r) * K + kc + kk];
          acc[r][0] += a.x * w0.x; acc[r][1] += a.x * w0.y;
          acc[r][2] += a.x * w0.z; acc[r][3] += a.x * w0.w;
          acc[r][0] += a.y * w1.x; acc[r][1] += a.y * w1.y;
          acc[r][2] += a.y * w1.z; acc[r][3] += a.y * w1.w;
        }
      }
    } else {
#pragma unroll
      for (int kk = 0; kk < KC; ++kk) {
        const float4 w0 = *(const float4*)&w_s[kk * M + tx * 4];
#pragma unroll
        for (int r = 0; r < RR; ++r) {
          const float a = in_s[(g * RR + r) * K + kc + kk];
          acc[r][0] += a * w0.x; acc[r][1] += a * w0.y;
          acc[r][2] += a * w0.z; acc[r][3] += a * w0.w;
        }
      }
    }
  }

  const float4 bv = *(const float4*)&bias[tx * 4];
#pragma unroll
  for (int r = 0; r < RR; ++r) {
    int row = r0 + g * RR + r;
    if (row < NN) {
      float4 o;
      o.x = fmaxf(acc[r][0] + bv.x, 0.f);
      o.y = fmaxf(acc[r][1] + bv.y, 0.f);
      o.z = fmaxf(acc[r][2] + bv.z, 0.f);
      o.w = fmaxf(acc[r][3] + bv.w, 0.f);
      *(float4*)&out[(size_t)row * M + tx * 4] = o;
    }
  }
}

// ---------------- mean pool (batch is sorted) ----------------
__global__ __launch_bounds__(256) void k_pool(const float* __restrict__ h,
    const int* __restrict__ batch, float* __restrict__ pooled, float* __restrict__ cnt) {
  const int c = threadIdx.x;
  const int v0 = blockIdx.x * 128;
  if (v0 >= NN) return;
  const int vend = (v0 + 128 < NN) ? v0 + 128 : NN;
  float acc = 0.f;
  int curb = batch[v0];
  int run = 0;
  for (int v = v0; v < vend; ++v) {
    int b = batch[v];
    if (b != curb) {
      atomAdd(&pooled[curb * 256 + c], acc);
      if (c == 0) atomAdd(&cnt[curb], (float)run);
      acc = 0.f; run = 0; curb = b;
    }
    acc += h[(size_t)v * 256 + c];
    ++run;
  }
  atomAdd(&pooled[curb * 256 + c], acc);
  if (c == 0) atomAdd(&cnt[curb], (float)run);
}

// ---------------- MLP head + log_softmax ----------------
__global__ __launch_bounds__(128) void k_mlp(const float* __restrict__ pooled,
    const float* __restrict__ cnt, const float* __restrict__ w1,
    const float* __restrict__ b1, const float* __restrict__ w2,
    const float* __restrict__ b2, float* __restrict__ out) {
  __shared__ float p[256];
  __shared__ float h1[100];
  __shared__ float lo[10];
  const int b = blockIdx.x;
  const float inv = 1.0f / fmaxf(cnt[b], 1.0f);
  for (int i = threadIdx.x; i < 256; i += 128) p[i] = pooled[b * 256 + i] * inv;
  __syncthreads();
  for (int j = threadIdx.x; j < 100; j += 128) {
    float s = b1[j];
    for (int k = 0; k < 256; ++k) s += p[k] * w1[k * 100 + j];
    h1[j] = fmaxf(s, 0.f);
  }
  __syncthreads();
  if (threadIdx.x < 10) {
    int j = threadIdx.x;
    float s = b2[j];
    for (int k = 0; k < 100; ++k) s += h1[k] * w2[k * 10 + j];
    lo[j] = s;
  }
  __syncthreads();
  if (threadIdx.x == 0) {
    float m = lo[0];
    for (int j = 1; j < 10; ++j) m = fmaxf(m, lo[j]);
    float ssum = 0.f;
    for (int j = 0; j < 10; ++j) ssum += expf(lo[j] - m);
    float lse = m + logf(ssum);
    for (int j = 0; j < 10; ++j) out[b * 10 + j] = lo[j] - lse;
  }
}

extern "C" void kernel_launch(void* const* d_in, const int* in_sizes, int n_in,
                              void* d_out, int out_size, void* d_ws, size_t ws_size,
                              hipStream_t stream) {
  const float* x     = (const float*)d_in[0];
  const int*   ei    = (const int*)d_in[1];
  const int*   batch = (const int*)d_in[2];
  const float* W1 = (const float*)d_in[3];  const float* b1 = (const float*)d_in[4];
  const float* W2 = (const float*)d_in[5];  const float* b2 = (const float*)d_in[6];
  const float* W3 = (const float*)d_in[7];  const float* b3 = (const float*)d_in[8];
  const float* W4 = (const float*)d_in[9];  const float* b4 = (const float*)d_in[10];
  const float* fc1w = (const float*)d_in[11]; const float* fc1b = (const float*)d_in[12];
  const float* fc2w = (const float*)d_in[13]; const float* fc2b = (const float*)d_in[14];
  float* out = (float*)d_out;

  const int* src = ei;        // edge_index[0]
  const int* dst = ei + NE;   // edge_index[1]

  // ---- workspace layout (4-byte words) ----
  float* ws = (float*)d_ws;
  float* dinv   = ws;                      // 100352
  float* A      = dinv + 100352;           // NN*128 = 12,800,000
  float* B      = A    + 12800000;         // NN*256 = 25,600,000
  float* R      = B    + 25600000;         // NN*128 = 12,800,000
  float* pooled = R    + 12800000;         // 16384
  float* pcnt   = pooled + 16384;          // 64
  int*   cnt     = (int*)(pcnt + 64);      // 100352
  int*   excl    = cnt + 100352;           // 100352
  int*   partial = excl + 100352;          // 256
  int*   rowptr  = partial + 256;          // 100352 (N+1 used)
  int*   fillpos = rowptr + 100352;        // 100352
  int*   csrc    = fillpos + 100352;       // NE

  // ---- build CSR (by dst) + dinv ----
  hipMemsetAsync(cnt, 0, 100352 * sizeof(int), stream);
  k_deg<<<(NE + 255) / 256, 256, 0, stream>>>(dst, cnt);
  k_dinv<<<(NN + 255) / 256, 256, 0, stream>>>(cnt, dinv);
  k_scan1<<<196, 512, 0, stream>>>(cnt, excl, partial);
  k_scan2<<<1, 256, 0, stream>>>(partial);
  k_scan3<<<196, 512, 0, stream>>>(excl, partial, rowptr, fillpos);
  k_fill<<<(NE + 255) / 256, 256, 0, stream>>>(src, dst, fillpos, csrc);

  // ---- layer 1: gather x (K=5), GEMM 5->32 ----
  k_gather5<<<3125, 256, 0, stream>>>(x, rowptr, csrc, dinv, R);
  k_gemm<5, 32><<<(NN + 63) / 64, 256, 0, stream>>>(R, W1, b1, A);

  // ---- layer 2: K=32 -> M=64 ----
  k_gather<32><<<NN / 8 / (256 / 8) * 1 + 0, 256, 0, stream>>>(A, rowptr, csrc, dinv, R);  // 3125 blocks
  k_gemm<32, 64><<<(NN + 63) / 64, 256, 0, stream>>>(R, W2, b2, B);

  // ---- layer 3: K=64 -> M=128 ----
  k_gather<64><<<6250, 256, 0, stream>>>(B, rowptr, csrc, dinv, R);
  k_gemm<64, 128><<<(NN + 63) / 64, 256, 0, stream>>>(R, W3, b3, A);

  // ---- layer 4: K=128 -> M=256 ----
  k_gather<128><<<12500, 256, 0, stream>>>(A, rowptr, csrc, dinv, R);
  k_gemm<128, 256><<<(NN + 63) / 64, 256, 0, stream>>>(R, W4, b4, B);

  // ---- mean pool + MLP head ----
  hipMemsetAsync(pooled, 0, (16384 + 64) * sizeof(float), stream);
  k_pool<<<(NN + 127) / 128, 256, 0, stream>>>(B, batch, pooled, pcnt);
  k_mlp<<<NBATCH, 128, 0, stream>>>(pooled, pcnt, fc1w, fc1b, fc2w, fc2b, out);
}

// Round 3
// 563.523 us; speedup vs baseline: 3.8472x; 1.5339x over previous
//
#include <hip/hip_runtime.h>
#include <hip/hip_bf16.h>
#include <cmath>

#define NN 100000
#define NE 1600000
#define NBATCH 64

typedef __attribute__((ext_vector_type(8))) short bf16x8;
typedef __attribute__((ext_vector_type(4))) float f32x4;

__device__ __forceinline__ void atomAdd(float* p, float v) {
  unsafeAtomicAdd(p, v);
}

__device__ __forceinline__ unsigned short f2bf(float f) {
  __hip_bfloat16 h = __float2bfloat16(f);
  union { __hip_bfloat16 h; unsigned short u; } cv; cv.h = h; return cv.u;
}
__device__ __forceinline__ float bflo(unsigned int u) { return __uint_as_float(u << 16); }
__device__ __forceinline__ float bfhi(unsigned int u) { return __uint_as_float(u & 0xffff0000u); }

// ---------------- degree count (int) ----------------
__global__ __launch_bounds__(256) void k_deg(const int* __restrict__ dst, int* __restrict__ cnt) {
  int e = blockIdx.x * 256 + threadIdx.x;
  if (e < NE) atomicAdd(&cnt[dst[e]], 1);
}

__global__ __launch_bounds__(256) void k_dinv(const int* __restrict__ cnt, float* __restrict__ d) {
  int i = blockIdx.x * 256 + threadIdx.x;
  if (i < NN) d[i] = rsqrtf((float)cnt[i] + 1.0f);
}

// ---------------- exclusive scan (3 kernels) ----------------
__global__ __launch_bounds__(512) void k_scan1(const int* __restrict__ cnt,
    int* __restrict__ excl, int* __restrict__ partial) {
  __shared__ int sh[512];
  int i = blockIdx.x * 512 + threadIdx.x;
  int v = (i < NN) ? cnt[i] : 0;
  sh[threadIdx.x] = v;
  __syncthreads();
  for (int off = 1; off < 512; off <<= 1) {
    int t = (threadIdx.x >= (unsigned)off) ? sh[threadIdx.x - off] : 0;
    __syncthreads();
    sh[threadIdx.x] += t;
    __syncthreads();
  }
  if (i < NN) excl[i] = sh[threadIdx.x] - v;
  if (threadIdx.x == 511) partial[blockIdx.x] = sh[511];
}

__global__ __launch_bounds__(256) void k_scan2(int* __restrict__ partial) {
  __shared__ int sh[256];
  int v = (threadIdx.x < 196) ? partial[threadIdx.x] : 0;
  sh[threadIdx.x] = v;
  __syncthreads();
  for (int off = 1; off < 256; off <<= 1) {
    int t = (threadIdx.x >= (unsigned)off) ? sh[threadIdx.x - off] : 0;
    __syncthreads();
    sh[threadIdx.x] += t;
    __syncthreads();
  }
  if (threadIdx.x < 196) partial[threadIdx.x] = sh[threadIdx.x] - v;
}

__global__ __launch_bounds__(512) void k_scan3(const int* __restrict__ excl,
    const int* __restrict__ partial, int* __restrict__ rowptr, int* __restrict__ fillpos) {
  int i = blockIdx.x * 512 + threadIdx.x;
  if (i < NN) {
    int v = excl[i] + partial[blockIdx.x];
    rowptr[i] = v;
    fillpos[i] = v;
  }
  if (i == NN) rowptr[NN] = NE;
}

__global__ __launch_bounds__(256) void k_fill(const int* __restrict__ src,
    const int* __restrict__ dst, int* __restrict__ fillpos, int* __restrict__ csrc) {
  int e = blockIdx.x * 256 + threadIdx.x;
  if (e < NE) {
    int pos = atomicAdd(&fillpos[dst[e]], 1);
    csrc[pos] = src[e];
  }
}

// ---------------- weight convert + transpose: W[K][M] fp32 -> Wt[M][K] bf16 ----------------
__global__ __launch_bounds__(256) void k_wt(const float* __restrict__ W,
    unsigned short* __restrict__ Wt, int K, int M) {
  int idx = blockIdx.x * 256 + threadIdx.x;
  if (idx < K * M) {
    int k = idx / M, m = idx - k * M;
    Wt[m * K + k] = f2bf(W[idx]);
  }
}

// ---------------- layer-1 gather (fp32, K=5) ----------------
__global__ __launch_bounds__(256) void k_gather5(const float* __restrict__ in,
    const int* __restrict__ rowptr, const int* __restrict__ csrc,
    const float* __restrict__ dinv, float* __restrict__ agg) {
  const int r = blockIdx.x * 32 + threadIdx.x / 8;
  const int k = threadIdx.x % 8;
  if (k >= 5) return;
  const float di = dinv[r];
  float acc = in[(size_t)r * 5 + k] * di * di;
  const int e1 = rowptr[r + 1];
  for (int e = rowptr[r]; e < e1; ++e) {
    const int s = csrc[e];
    acc += in[(size_t)s * 5 + k] * dinv[s] * di;
  }
  agg[(size_t)r * 5 + k] = acc;
}

// ---------------- layer-1 GEMM 5->32 (fp32 vector, bf16 out) ----------------
__global__ __launch_bounds__(256) void k_gemm1(const float* __restrict__ R5,
    const float* __restrict__ W, const float* __restrict__ b,
    unsigned short* __restrict__ outp) {
  int r = blockIdx.x * 256 + threadIdx.x;
  if (r >= NN) return;
  float xr[5];
#pragma unroll
  for (int k = 0; k < 5; ++k) xr[k] = R5[(size_t)r * 5 + k];
  unsigned int o[16];
#pragma unroll
  for (int j2 = 0; j2 < 16; ++j2) {
    float s0 = b[j2 * 2], s1 = b[j2 * 2 + 1];
#pragma unroll
    for (int k = 0; k < 5; ++k) {
      s0 += xr[k] * W[k * 32 + j2 * 2];
      s1 += xr[k] * W[k * 32 + j2 * 2 + 1];
    }
    s0 = fmaxf(s0, 0.f); s1 = fmaxf(s1, 0.f);
    o[j2] = (unsigned int)f2bf(s0) | ((unsigned int)f2bf(s1) << 16);
  }
  uint4* op = (uint4*)(outp + (size_t)r * 32);
  op[0] = *(uint4*)&o[0];
  op[1] = *(uint4*)&o[4];
  op[2] = *(uint4*)&o[8];
  op[3] = *(uint4*)&o[12];
}

// ---------------- bf16 CSR gather: agg = D^-1/2 (A+I) D^-1/2 in ----------------
template<int K>
__global__ __launch_bounds__(256) void k_gatherb(const unsigned short* __restrict__ in,
    const int* __restrict__ rowptr, const int* __restrict__ csrc,
    const float* __restrict__ dinv, unsigned short* __restrict__ agg) {
  constexpr int TPR = K / 8;          // lanes per row (8 bf16 = 16B each)
  constexpr int RPB = 256 / TPR;
  const int r = blockIdx.x * RPB + threadIdx.x / TPR;
  if (r >= NN) return;
  const int c = (threadIdx.x % TPR) * 8;
  const float di = dinv[r];
  const float sl = di * di;
  float a0[8], a1[8];
  {
    const uint4 v = *(const uint4*)(in + (size_t)r * K + c);
    a0[0] = bflo(v.x) * sl; a0[1] = bfhi(v.x) * sl;
    a0[2] = bflo(v.y) * sl; a0[3] = bfhi(v.y) * sl;
    a0[4] = bflo(v.z) * sl; a0[5] = bfhi(v.z) * sl;
    a0[6] = bflo(v.w) * sl; a0[7] = bfhi(v.w) * sl;
#pragma unroll
    for (int j = 0; j < 8; ++j) a1[j] = 0.f;
  }
  int e = rowptr[r];
  const int e1 = rowptr[r + 1];
  for (; e + 2 <= e1; e += 2) {
    const int s0 = csrc[e], s1 = csrc[e + 1];
    const float w0 = dinv[s0] * di, w1 = dinv[s1] * di;
    const uint4 v0 = *(const uint4*)(in + (size_t)s0 * K + c);
    const uint4 v1 = *(const uint4*)(in + (size_t)s1 * K + c);
    a0[0] += bflo(v0.x) * w0; a0[1] += bfhi(v0.x) * w0;
    a0[2] += bflo(v0.y) * w0; a0[3] += bfhi(v0.y) * w0;
    a0[4] += bflo(v0.z) * w0; a0[5] += bfhi(v0.z) * w0;
    a0[6] += bflo(v0.w) * w0; a0[7] += bfhi(v0.w) * w0;
    a1[0] += bflo(v1.x) * w1; a1[1] += bfhi(v1.x) * w1;
    a1[2] += bflo(v1.y) * w1; a1[3] += bfhi(v1.y) * w1;
    a1[4] += bflo(v1.z) * w1; a1[5] += bfhi(v1.z) * w1;
    a1[6] += bflo(v1.w) * w1; a1[7] += bfhi(v1.w) * w1;
  }
  if (e < e1) {
    const int s0 = csrc[e];
    const float w0 = dinv[s0] * di;
    const uint4 v0 = *(const uint4*)(in + (size_t)s0 * K + c);
    a0[0] += bflo(v0.x) * w0; a0[1] += bfhi(v0.x) * w0;
    a0[2] += bflo(v0.y) * w0; a0[3] += bfhi(v0.y) * w0;
    a0[4] += bflo(v0.z) * w0; a0[5] += bfhi(v0.z) * w0;
    a0[6] += bflo(v0.w) * w0; a0[7] += bfhi(v0.w) * w0;
  }
  uint4 o;
  o.x = (unsigned int)f2bf(a0[0] + a1[0]) | ((unsigned int)f2bf(a0[1] + a1[1]) << 16);
  o.y = (unsigned int)f2bf(a0[2] + a1[2]) | ((unsigned int)f2bf(a0[3] + a1[3]) << 16);
  o.z = (unsigned int)f2bf(a0[4] + a1[4]) | ((unsigned int)f2bf(a0[5] + a1[5]) << 16);
  o.w = (unsigned int)f2bf(a0[6] + a1[6]) | ((unsigned int)f2bf(a0[7] + a1[7]) << 16);
  *(uint4*)(agg + (size_t)r * K + c) = o;
}

// ---------------- MFMA GEMM: out = ReLU(agg @ W + b), bf16 in/out ----------------
// Block: 256 threads = 4 waves; tile 64 rows x M cols; wave owns M/4 cols x all 4 row-tiles.
template<int K, int M>
__global__ __launch_bounds__(256) void k_gemm_mfma(const unsigned short* __restrict__ agg,
    const unsigned short* __restrict__ Wt,   // [M][K] bf16 (pre-transposed)
    const float* __restrict__ bias, unsigned short* __restrict__ outp) {
  constexpr int KP = K + 8;      // padded A row stride (bf16 elems) — 2-way bank alias only
  constexpr int KC = 32;         // K chunk
  constexpr int WP = KC + 8;     // padded Wt row stride
  constexpr int CTW = M / 64;    // 16-col tiles per wave
  constexpr int C8 = K / 8;
  __shared__ unsigned short a_s[64 * KP];
  __shared__ unsigned short w_s[M * WP];
  const int r0 = blockIdx.x * 64;
  const int tid = threadIdx.x;

  // stage A (full K rows)
  for (int idx = tid; idx < 64 * C8; idx += 256) {
    int row = idx / C8, cc = (idx % C8) * 8;
    uint4 v = {0u, 0u, 0u, 0u};
    if (r0 + row < NN) v = *(const uint4*)(agg + (size_t)(r0 + row) * K + cc);
    *(uint4*)&a_s[row * KP + cc] = v;
  }

  const int wave = tid >> 6, lane = tid & 63;
  const int m16 = lane & 15, q = lane >> 4;
  f32x4 acc[4][CTW];
#pragma unroll
  for (int rt = 0; rt < 4; ++rt)
#pragma unroll
    for (int ct = 0; ct < CTW; ++ct) acc[rt][ct] = (f32x4){0.f, 0.f, 0.f, 0.f};

  for (int kc = 0; kc < K; kc += KC) {
    __syncthreads();
    // stage Wt chunk: w_s[m][kk] = Wt[m][kc+kk], kk in [0,KC)
    for (int idx = tid; idx < M * (KC / 8); idx += 256) {
      int m = idx / (KC / 8), cc = (idx % (KC / 8)) * 8;
      uint4 v = *(const uint4*)(Wt + (size_t)m * K + kc + cc);
      *(uint4*)&w_s[m * WP + cc] = v;
    }
    __syncthreads();
    bf16x8 bfr[CTW];
#pragma unroll
    for (int ct = 0; ct < CTW; ++ct)
      bfr[ct] = *(const bf16x8*)&w_s[(wave * (M / 4) + ct * 16 + m16) * WP + q * 8];
#pragma unroll
    for (int rt = 0; rt < 4; ++rt) {
      bf16x8 afr = *(const bf16x8*)&a_s[(rt * 16 + m16) * KP + kc + q * 8];
#pragma unroll
      for (int ct = 0; ct < CTW; ++ct)
        acc[rt][ct] = __builtin_amdgcn_mfma_f32_16x16x32_bf16(afr, bfr[ct], acc[rt][ct], 0, 0, 0);
    }
  }

  // epilogue: C/D layout col=lane&15, row=(lane>>4)*4+reg
#pragma unroll
  for (int rt = 0; rt < 4; ++rt) {
#pragma unroll
    for (int ct = 0; ct < CTW; ++ct) {
      const int col = wave * (M / 4) + ct * 16 + m16;
      const float bv = bias[col];
#pragma unroll
      for (int reg = 0; reg < 4; ++reg) {
        const int row = r0 + rt * 16 + q * 4 + reg;
        if (row < NN) {
          float vv = fmaxf(acc[rt][ct][reg] + bv, 0.f);
          outp[(size_t)row * M + col] = f2bf(vv);
        }
      }
    }
  }
}

// ---------------- mean pool (batch sorted, bf16 in) ----------------
__global__ __launch_bounds__(256) void k_pool(const unsigned short* __restrict__ h,
    const int* __restrict__ batch, float* __restrict__ pooled, float* __restrict__ cnt) {
  const int c = threadIdx.x;
  const int v0 = blockIdx.x * 128;
  if (v0 >= NN) return;
  const int vend = (v0 + 128 < NN) ? v0 + 128 : NN;
  float acc = 0.f;
  int curb = batch[v0];
  int run = 0;
  for (int v = v0; v < vend; ++v) {
    int b = batch[v];
    if (b != curb) {
      atomAdd(&pooled[curb * 256 + c], acc);
      if (c == 0) atomAdd(&cnt[curb], (float)run);
      acc = 0.f; run = 0; curb = b;
    }
    acc += bflo((unsigned int)h[(size_t)v * 256 + c]);
    ++run;
  }
  atomAdd(&pooled[curb * 256 + c], acc);
  if (c == 0) atomAdd(&cnt[curb], (float)run);
}

// ---------------- MLP head + log_softmax ----------------
__global__ __launch_bounds__(128) void k_mlp(const float* __restrict__ pooled,
    const float* __restrict__ cnt, const float* __restrict__ w1,
    const float* __restrict__ b1, const float* __restrict__ w2,
    const float* __restrict__ b2, float* __restrict__ out) {
  __shared__ float p[256];
  __shared__ float h1[100];
  __shared__ float lo[10];
  const int b = blockIdx.x;
  const float inv = 1.0f / fmaxf(cnt[b], 1.0f);
  for (int i = threadIdx.x; i < 256; i += 128) p[i] = pooled[b * 256 + i] * inv;
  __syncthreads();
  for (int j = threadIdx.x; j < 100; j += 128) {
    float s = b1[j];
    for (int k = 0; k < 256; ++k) s += p[k] * w1[k * 100 + j];
    h1[j] = fmaxf(s, 0.f);
  }
  __syncthreads();
  if (threadIdx.x < 10) {
    int j = threadIdx.x;
    float s = b2[j];
    for (int k = 0; k < 100; ++k) s += h1[k] * w2[k * 10 + j];
    lo[j] = s;
  }
  __syncthreads();
  if (threadIdx.x == 0) {
    float m = lo[0];
    for (int j = 1; j < 10; ++j) m = fmaxf(m, lo[j]);
    float ssum = 0.f;
    for (int j = 0; j < 10; ++j) ssum += expf(lo[j] - m);
    float lse = m + logf(ssum);
    for (int j = 0; j < 10; ++j) out[b * 10 + j] = lo[j] - lse;
  }
}

extern "C" void kernel_launch(void* const* d_in, const int* in_sizes, int n_in,
                              void* d_out, int out_size, void* d_ws, size_t ws_size,
                              hipStream_t stream) {
  const float* x     = (const float*)d_in[0];
  const int*   ei    = (const int*)d_in[1];
  const int*   batch = (const int*)d_in[2];
  const float* W1 = (const float*)d_in[3];  const float* b1 = (const float*)d_in[4];
  const float* W2 = (const float*)d_in[5];  const float* b2 = (const float*)d_in[6];
  const float* W3 = (const float*)d_in[7];  const float* b3 = (const float*)d_in[8];
  const float* W4 = (const float*)d_in[9];  const float* b4 = (const float*)d_in[10];
  const float* fc1w = (const float*)d_in[11]; const float* fc1b = (const float*)d_in[12];
  const float* fc2w = (const float*)d_in[13]; const float* fc2b = (const float*)d_in[14];
  float* out = (float*)d_out;

  const int* src = ei;        // edge_index[0]
  const int* dst = ei + NE;   // edge_index[1]

  // ---- workspace layout ----
  float* ws = (float*)d_ws;
  float* dinv   = ws;                      // 100352
  float* R5     = dinv + 100352;           // 500480
  float* pooled = R5 + 500480;             // 16384
  float* pcnt   = pooled + 16384;          // 64
  int*   cnt     = (int*)(pcnt + 64);      // 100352
  int*   excl    = cnt + 100352;           // 100352
  int*   partial = excl + 100352;          // 256
  int*   rowptr  = partial + 256;          // 100352
  int*   fillpos = rowptr + 100352;        // 100352
  int*   csrc    = fillpos + 100352;       // NE
  unsigned short* F0  = (unsigned short*)(csrc + NE);  // NN*32
  unsigned short* F1  = F0 + (size_t)NN * 32;          // NN*64
  unsigned short* F2  = F1 + (size_t)NN * 64;          // NN*128
  unsigned short* F3  = F2 + (size_t)NN * 128;         // NN*256
  unsigned short* AG  = F3 + (size_t)NN * 256;         // NN*128
  unsigned short* Wt2 = AG + (size_t)NN * 128;         // 32*64
  unsigned short* Wt3 = Wt2 + 32 * 64;                 // 64*128
  unsigned short* Wt4 = Wt3 + 64 * 128;                // 128*256

  // ---- build CSR (by dst) + dinv + weight transposes ----
  hipMemsetAsync(cnt, 0, 100352 * sizeof(int), stream);
  k_deg<<<(NE + 255) / 256, 256, 0, stream>>>(dst, cnt);
  k_dinv<<<(NN + 255) / 256, 256, 0, stream>>>(cnt, dinv);
  k_scan1<<<196, 512, 0, stream>>>(cnt, excl, partial);
  k_scan2<<<1, 256, 0, stream>>>(partial);
  k_scan3<<<196, 512, 0, stream>>>(excl, partial, rowptr, fillpos);
  k_fill<<<(NE + 255) / 256, 256, 0, stream>>>(src, dst, fillpos, csrc);
  k_wt<<<(32 * 64 + 255) / 256, 256, 0, stream>>>(W2, Wt2, 32, 64);
  k_wt<<<(64 * 128 + 255) / 256, 256, 0, stream>>>(W3, Wt3, 64, 128);
  k_wt<<<(128 * 256 + 255) / 256, 256, 0, stream>>>(W4, Wt4, 128, 256);

  // ---- layer 1: gather x (K=5) fp32, GEMM 5->32, bf16 out ----
  k_gather5<<<3125, 256, 0, stream>>>(x, rowptr, csrc, dinv, R5);
  k_gemm1<<<(NN + 255) / 256, 256, 0, stream>>>(R5, W1, b1, F0);

  // ---- layer 2: K=32 -> M=64 ----
  k_gatherb<32><<<(NN + 63) / 64, 256, 0, stream>>>(F0, rowptr, csrc, dinv, AG);
  k_gemm_mfma<32, 64><<<(NN + 63) / 64, 256, 0, stream>>>(AG, Wt2, b2, F1);

  // ---- layer 3: K=64 -> M=128 ----
  k_gatherb<64><<<(NN + 31) / 32, 256, 0, stream>>>(F1, rowptr, csrc, dinv, AG);
  k_gemm_mfma<64, 128><<<(NN + 63) / 64, 256, 0, stream>>>(AG, Wt3, b3, F2);

  // ---- layer 4: K=128 -> M=256 ----
  k_gatherb<128><<<(NN + 15) / 16, 256, 0, stream>>>(F2, rowptr, csrc, dinv, AG);
  k_gemm_mfma<128, 256><<<(NN + 63) / 64, 256, 0, stream>>>(AG, Wt4, b4, F3);

  // ---- mean pool + MLP head ----
  hipMemsetAsync(pooled, 0, (16384 + 64) * sizeof(float), stream);
  k_pool<<<(NN + 127) / 128, 256, 0, stream>>>(F3, batch, pooled, pcnt);
  k_mlp<<<NBATCH, 128, 0, stream>>>(pooled, pcnt, fc1w, fc1b, fc2w, fc2b, out);
}

// Round 4
// 424.677 us; speedup vs baseline: 5.1051x; 1.3269x over previous
//
#include <hip/hip_runtime.h>
#include <hip/hip_bf16.h>
#include <cmath>

#define NN 100000
#define NE 1600000
#define NBATCH 64
#define NB 391      // buckets of 256 nodes (dst>>8); 100000/256 -> 391
#define NBP 512     // padded bucket count

typedef __attribute__((ext_vector_type(8))) short bf16x8;
typedef __attribute__((ext_vector_type(4))) float f32x4;

__device__ __forceinline__ void atomAdd(float* p, float v) {
  unsafeAtomicAdd(p, v);
}

__device__ __forceinline__ unsigned short f2bf(float f) {
  __hip_bfloat16 h = __float2bfloat16(f);
  union { __hip_bfloat16 h; unsigned short u; } cv; cv.h = h; return cv.u;
}
__device__ __forceinline__ float bflo(unsigned int u) { return __uint_as_float(u << 16); }
__device__ __forceinline__ float bfhi(unsigned int u) { return __uint_as_float(u & 0xffff0000u); }

// ---------------- bucket histogram (LDS-staged) ----------------
__global__ __launch_bounds__(256) void k_hist(const int* __restrict__ dst,
    int* __restrict__ bucketCnt) {
  __shared__ int h[NBP];
  for (int i = threadIdx.x; i < NBP; i += 256) h[i] = 0;
  __syncthreads();
  const int base = blockIdx.x * 4096;
  const int n = (NE - base < 4096) ? NE - base : 4096;
  for (int i = threadIdx.x; i < n; i += 256) atomicAdd(&h[dst[base + i] >> 8], 1);
  __syncthreads();
  for (int i = threadIdx.x; i < NB; i += 256)
    if (h[i]) atomicAdd(&bucketCnt[i], h[i]);
}

// ---------------- bucket base scan (1 block) ----------------
__global__ __launch_bounds__(512) void k_bscan(const int* __restrict__ bucketCnt,
    int* __restrict__ bucketBase, int* __restrict__ bucketPos) {
  __shared__ int s[NBP];
  int v = (threadIdx.x < NB) ? bucketCnt[threadIdx.x] : 0;
  s[threadIdx.x] = v;
  __syncthreads();
  for (int off = 1; off < NBP; off <<= 1) {
    int t = (threadIdx.x >= (unsigned)off) ? s[threadIdx.x - off] : 0;
    __syncthreads();
    s[threadIdx.x] += t;
    __syncthreads();
  }
  if (threadIdx.x < NB) {
    int ex = s[threadIdx.x] - v;
    bucketBase[threadIdx.x] = ex;
    bucketPos[threadIdx.x] = ex;
  }
}

// ---------------- bin edges into bucket regions (LDS counting sort per 4096-chunk) ----------------
__global__ __launch_bounds__(256) void k_bin(const int* __restrict__ src,
    const int* __restrict__ dst, int* __restrict__ bucketPos, uint2* __restrict__ pairs) {
  __shared__ int hist[NBP];
  __shared__ int scn[NBP];     // inclusive scan of hist
  __shared__ int ofs[NBP];     // running slot counters (start at exclusive scan)
  __shared__ int gbase[NBP];
  __shared__ uint2 buf[4096];
  const int base = blockIdx.x * 4096;
  const int n = (NE - base < 4096) ? NE - base : 4096;
  for (int i = threadIdx.x; i < NBP; i += 256) hist[i] = 0;
  __syncthreads();

  int myS[16], myD[16];
  int nloc = 0;
  for (int i = threadIdx.x, j = 0; i < n; i += 256, ++j) {
    myS[j] = src[base + i];
    myD[j] = dst[base + i];
    atomicAdd(&hist[myD[j] >> 8], 1);
    nloc = j + 1;
  }
  __syncthreads();

  // Hillis-Steele inclusive scan over NBP entries, 2 per thread
  scn[threadIdx.x] = hist[threadIdx.x];
  scn[threadIdx.x + 256] = hist[threadIdx.x + 256];
  __syncthreads();
  for (int off = 1; off < NBP; off <<= 1) {
    const int i0 = threadIdx.x, i1 = threadIdx.x + 256;
    int t0 = (i0 >= off) ? scn[i0 - off] : 0;
    int t1 = (i1 >= off) ? scn[i1 - off] : 0;
    __syncthreads();
    scn[i0] += t0;
    scn[i1] += t1;
    __syncthreads();
  }
  ofs[threadIdx.x] = scn[threadIdx.x] - hist[threadIdx.x];
  ofs[threadIdx.x + 256] = scn[threadIdx.x + 256] - hist[threadIdx.x + 256];
  // reserve global space per bucket
  for (int b = threadIdx.x; b < NB; b += 256) {
    int c = hist[b];
    if (c) gbase[b] = atomicAdd(&bucketPos[b], c);
  }
  __syncthreads();

  // scatter into LDS in bucket-sorted order
  for (int j = 0; j < nloc; ++j) {
    int b = myD[j] >> 8;
    int slot = atomicAdd(&ofs[b], 1);
    buf[slot] = make_uint2((unsigned)myS[j], (unsigned)myD[j]);
  }
  __syncthreads();

  // coalesced copy-out: slot i -> global gbase[b] + (i - exclusive[b])
  for (int i = threadIdx.x; i < n; i += 256) {
    uint2 p = buf[i];
    int b = (int)(p.y >> 8);
    int ex = scn[b] - hist[b];
    pairs[gbase[b] + (i - ex)] = p;
  }
}

// ---------------- per-bucket degree count + dinv (LDS counters) ----------------
__global__ __launch_bounds__(256) void k_cnt(const uint2* __restrict__ pairs,
    const int* __restrict__ bucketBase, const int* __restrict__ bucketPos,
    int* __restrict__ cnt, float* __restrict__ dinv) {
  __shared__ int c[256];
  c[threadIdx.x] = 0;
  __syncthreads();
  const int b = blockIdx.x;
  const int s = bucketBase[b], e = bucketPos[b];
  for (int i = s + threadIdx.x; i < e; i += 256)
    atomicAdd(&c[pairs[i].y & 255], 1);
  __syncthreads();
  const int node = b * 256 + threadIdx.x;
  if (node < NN) {
    cnt[node] = c[threadIdx.x];
    dinv[node] = rsqrtf((float)c[threadIdx.x] + 1.0f);
  }
}

// ---------------- exclusive scan over nodes (3 kernels) ----------------
__global__ __launch_bounds__(512) void k_scan1(const int* __restrict__ cnt,
    int* __restrict__ excl, int* __restrict__ partial) {
  __shared__ int sh[512];
  int i = blockIdx.x * 512 + threadIdx.x;
  int v = (i < NN) ? cnt[i] : 0;
  sh[threadIdx.x] = v;
  __syncthreads();
  for (int off = 1; off < 512; off <<= 1) {
    int t = (threadIdx.x >= (unsigned)off) ? sh[threadIdx.x - off] : 0;
    __syncthreads();
    sh[threadIdx.x] += t;
    __syncthreads();
  }
  if (i < NN) excl[i] = sh[threadIdx.x] - v;
  if (threadIdx.x == 511) partial[blockIdx.x] = sh[511];
}

__global__ __launch_bounds__(256) void k_scan2(int* __restrict__ partial) {
  __shared__ int sh[256];
  int v = (threadIdx.x < 196) ? partial[threadIdx.x] : 0;
  sh[threadIdx.x] = v;
  __syncthreads();
  for (int off = 1; off < 256; off <<= 1) {
    int t = (threadIdx.x >= (unsigned)off) ? sh[threadIdx.x - off] : 0;
    __syncthreads();
    sh[threadIdx.x] += t;
    __syncthreads();
  }
  if (threadIdx.x < 196) partial[threadIdx.x] = sh[threadIdx.x] - v;
}

__global__ __launch_bounds__(512) void k_scan3(const int* __restrict__ excl,
    const int* __restrict__ partial, int* __restrict__ rowptr) {
  int i = blockIdx.x * 512 + threadIdx.x;
  if (i < NN) rowptr[i] = excl[i] + partial[blockIdx.x];
  if (i == NN) rowptr[NN] = NE;
}

// ---------------- bucket-local CSR fill (L2-local scatter) ----------------
__global__ __launch_bounds__(256) void k_fill_local(const uint2* __restrict__ pairs,
    const int* __restrict__ bucketBase, const int* __restrict__ bucketPos,
    const int* __restrict__ rowptr, int* __restrict__ csrc) {
  __shared__ int ofs[256];
  ofs[threadIdx.x] = 0;
  __syncthreads();
  const int b = blockIdx.x;
  const int s = bucketBase[b], e = bucketPos[b];
  for (int i = s + threadIdx.x; i < e; i += 256) {
    uint2 p = pairs[i];
    int d = (int)p.y;
    int pos = rowptr[d] + atomicAdd(&ofs[d & 255], 1);
    csrc[pos] = (int)p.x;
  }
}

// ---------------- layer-1 gather (fp32, K=5) ----------------
__global__ __launch_bounds__(256) void k_gather5(const float* __restrict__ in,
    const int* __restrict__ rowptr, const int* __restrict__ csrc,
    const float* __restrict__ dinv, float* __restrict__ agg) {
  const int r = blockIdx.x * 32 + threadIdx.x / 8;
  const int k = threadIdx.x % 8;
  if (k >= 5) return;
  const float di = dinv[r];
  float acc = in[(size_t)r * 5 + k] * di * di;
  const int e1 = rowptr[r + 1];
  for (int e = rowptr[r]; e < e1; ++e) {
    const int s = csrc[e];
    acc += in[(size_t)s * 5 + k] * dinv[s] * di;
  }
  agg[(size_t)r * 5 + k] = acc;
}

// ---------------- layer-1 GEMM 5->32 (fp32 vector, bf16 out) ----------------
__global__ __launch_bounds__(256) void k_gemm1(const float* __restrict__ R5,
    const float* __restrict__ W, const float* __restrict__ b,
    unsigned short* __restrict__ outp) {
  int r = blockIdx.x * 256 + threadIdx.x;
  if (r >= NN) return;
  float xr[5];
#pragma unroll
  for (int k = 0; k < 5; ++k) xr[k] = R5[(size_t)r * 5 + k];
  unsigned int o[16];
#pragma unroll
  for (int j2 = 0; j2 < 16; ++j2) {
    float s0 = b[j2 * 2], s1 = b[j2 * 2 + 1];
#pragma unroll
    for (int k = 0; k < 5; ++k) {
      s0 += xr[k] * W[k * 32 + j2 * 2];
      s1 += xr[k] * W[k * 32 + j2 * 2 + 1];
    }
    s0 = fmaxf(s0, 0.f); s1 = fmaxf(s1, 0.f);
    o[j2] = (unsigned int)f2bf(s0) | ((unsigned int)f2bf(s1) << 16);
  }
  uint4* op = (uint4*)(outp + (size_t)r * 32);
  op[0] = *(uint4*)&o[0];
  op[1] = *(uint4*)&o[4];
  op[2] = *(uint4*)&o[8];
  op[3] = *(uint4*)&o[12];
}

// ---------------- weight convert + transpose: W[K][M] fp32 -> Wt[M][K] bf16 ----------------
__global__ __launch_bounds__(256) void k_wt(const float* __restrict__ W,
    unsigned short* __restrict__ Wt, int K, int M) {
  int idx = blockIdx.x * 256 + threadIdx.x;
  if (idx < K * M) {
    int k = idx / M, m = idx - k * M;
    Wt[m * K + k] = f2bf(W[idx]);
  }
}

// ---------------- bf16 CSR gather: agg = D^-1/2 (A+I) D^-1/2 in ----------------
template<int K>
__global__ __launch_bounds__(256) void k_gatherb(const unsigned short* __restrict__ in,
    const int* __restrict__ rowptr, const int* __restrict__ csrc,
    const float* __restrict__ dinv, unsigned short* __restrict__ agg) {
  constexpr int TPR = K / 8;
  constexpr int RPB = 256 / TPR;
  const int r = blockIdx.x * RPB + threadIdx.x / TPR;
  if (r >= NN) return;
  const int c = (threadIdx.x % TPR) * 8;
  const float di = dinv[r];
  const float sl = di * di;
  float a0[8], a1[8];
  {
    const uint4 v = *(const uint4*)(in + (size_t)r * K + c);
    a0[0] = bflo(v.x) * sl; a0[1] = bfhi(v.x) * sl;
    a0[2] = bflo(v.y) * sl; a0[3] = bfhi(v.y) * sl;
    a0[4] = bflo(v.z) * sl; a0[5] = bfhi(v.z) * sl;
    a0[6] = bflo(v.w) * sl; a0[7] = bfhi(v.w) * sl;
#pragma unroll
    for (int j = 0; j < 8; ++j) a1[j] = 0.f;
  }
  int e = rowptr[r];
  const int e1 = rowptr[r + 1];
  for (; e + 2 <= e1; e += 2) {
    const int s0 = csrc[e], s1 = csrc[e + 1];
    const float w0 = dinv[s0] * di, w1 = dinv[s1] * di;
    const uint4 v0 = *(const uint4*)(in + (size_t)s0 * K + c);
    const uint4 v1 = *(const uint4*)(in + (size_t)s1 * K + c);
    a0[0] += bflo(v0.x) * w0; a0[1] += bfhi(v0.x) * w0;
    a0[2] += bflo(v0.y) * w0; a0[3] += bfhi(v0.y) * w0;
    a0[4] += bflo(v0.z) * w0; a0[5] += bfhi(v0.z) * w0;
    a0[6] += bflo(v0.w) * w0; a0[7] += bfhi(v0.w) * w0;
    a1[0] += bflo(v1.x) * w1; a1[1] += bfhi(v1.x) * w1;
    a1[2] += bflo(v1.y) * w1; a1[3] += bfhi(v1.y) * w1;
    a1[4] += bflo(v1.z) * w1; a1[5] += bfhi(v1.z) * w1;
    a1[6] += bflo(v1.w) * w1; a1[7] += bfhi(v1.w) * w1;
  }
  if (e < e1) {
    const int s0 = csrc[e];
    const float w0 = dinv[s0] * di;
    const uint4 v0 = *(const uint4*)(in + (size_t)s0 * K + c);
    a0[0] += bflo(v0.x) * w0; a0[1] += bfhi(v0.x) * w0;
    a0[2] += bflo(v0.y) * w0; a0[3] += bfhi(v0.y) * w0;
    a0[4] += bflo(v0.z) * w0; a0[5] += bfhi(v0.z) * w0;
    a0[6] += bflo(v0.w) * w0; a0[7] += bfhi(v0.w) * w0;
  }
  uint4 o;
  o.x = (unsigned int)f2bf(a0[0] + a1[0]) | ((unsigned int)f2bf(a0[1] + a1[1]) << 16);
  o.y = (unsigned int)f2bf(a0[2] + a1[2]) | ((unsigned int)f2bf(a0[3] + a1[3]) << 16);
  o.z = (unsigned int)f2bf(a0[4] + a1[4]) | ((unsigned int)f2bf(a0[5] + a1[5]) << 16);
  o.w = (unsigned int)f2bf(a0[6] + a1[6]) | ((unsigned int)f2bf(a0[7] + a1[7]) << 16);
  *(uint4*)(agg + (size_t)r * K + c) = o;
}

// ---------------- MFMA GEMM: out = ReLU(agg @ W + b), bf16 in/out ----------------
template<int K, int M>
__global__ __launch_bounds__(256) void k_gemm_mfma(const unsigned short* __restrict__ agg,
    const unsigned short* __restrict__ Wt, const float* __restrict__ bias,
    unsigned short* __restrict__ outp) {
  constexpr int KP = K + 8;
  constexpr int KC = 32;
  constexpr int WP = KC + 8;
  constexpr int CTW = M / 64;
  constexpr int C8 = K / 8;
  __shared__ unsigned short a_s[64 * KP];
  __shared__ unsigned short w_s[M * WP];
  const int r0 = blockIdx.x * 64;
  const int tid = threadIdx.x;

  for (int idx = tid; idx < 64 * C8; idx += 256) {
    int row = idx / C8, cc = (idx % C8) * 8;
    uint4 v = {0u, 0u, 0u, 0u};
    if (r0 + row < NN) v = *(const uint4*)(agg + (size_t)(r0 + row) * K + cc);
    *(uint4*)&a_s[row * KP + cc] = v;
  }

  const int wave = tid >> 6, lane = tid & 63;
  const int m16 = lane & 15, q = lane >> 4;
  f32x4 acc[4][CTW];
#pragma unroll
  for (int rt = 0; rt < 4; ++rt)
#pragma unroll
    for (int ct = 0; ct < CTW; ++ct) acc[rt][ct] = (f32x4){0.f, 0.f, 0.f, 0.f};

  for (int kc = 0; kc < K; kc += KC) {
    __syncthreads();
    for (int idx = tid; idx < M * (KC / 8); idx += 256) {
      int m = idx / (KC / 8), cc = (idx % (KC / 8)) * 8;
      uint4 v = *(const uint4*)(Wt + (size_t)m * K + kc + cc);
      *(uint4*)&w_s[m * WP + cc] = v;
    }
    __syncthreads();
    bf16x8 bfr[CTW];
#pragma unroll
    for (int ct = 0; ct < CTW; ++ct)
      bfr[ct] = *(const bf16x8*)&w_s[(wave * (M / 4) + ct * 16 + m16) * WP + q * 8];
#pragma unroll
    for (int rt = 0; rt < 4; ++rt) {
      bf16x8 afr = *(const bf16x8*)&a_s[(rt * 16 + m16) * KP + kc + q * 8];
#pragma unroll
      for (int ct = 0; ct < CTW; ++ct)
        acc[rt][ct] = __builtin_amdgcn_mfma_f32_16x16x32_bf16(afr, bfr[ct], acc[rt][ct], 0, 0, 0);
    }
  }

#pragma unroll
  for (int rt = 0; rt < 4; ++rt) {
#pragma unroll
    for (int ct = 0; ct < CTW; ++ct) {
      const int col = wave * (M / 4) + ct * 16 + m16;
      const float bv = bias[col];
#pragma unroll
      for (int reg = 0; reg < 4; ++reg) {
        const int row = r0 + rt * 16 + q * 4 + reg;
        if (row < NN) {
          float vv = fmaxf(acc[rt][ct][reg] + bv, 0.f);
          outp[(size_t)row * M + col] = f2bf(vv);
        }
      }
    }
  }
}

// ---------------- mean pool (batch sorted, bf16 in) ----------------
__global__ __launch_bounds__(256) void k_pool(const unsigned short* __restrict__ h,
    const int* __restrict__ batch, float* __restrict__ pooled, float* __restrict__ cnt) {
  const int c = threadIdx.x;
  const int v0 = blockIdx.x * 128;
  if (v0 >= NN) return;
  const int vend = (v0 + 128 < NN) ? v0 + 128 : NN;
  float acc = 0.f;
  int curb = batch[v0];
  int run = 0;
  for (int v = v0; v < vend; ++v) {
    int b = batch[v];
    if (b != curb) {
      atomAdd(&pooled[curb * 256 + c], acc);
      if (c == 0) atomAdd(&cnt[curb], (float)run);
      acc = 0.f; run = 0; curb = b;
    }
    acc += bflo((unsigned int)h[(size_t)v * 256 + c]);
    ++run;
  }
  atomAdd(&pooled[curb * 256 + c], acc);
  if (c == 0) atomAdd(&cnt[curb], (float)run);
}

// ---------------- MLP head + log_softmax ----------------
__global__ __launch_bounds__(128) void k_mlp(const float* __restrict__ pooled,
    const float* __restrict__ cnt, const float* __restrict__ w1,
    const float* __restrict__ b1, const float* __restrict__ w2,
    const float* __restrict__ b2, float* __restrict__ out) {
  __shared__ float p[256];
  __shared__ float h1[100];
  __shared__ float lo[10];
  const int b = blockIdx.x;
  const float inv = 1.0f / fmaxf(cnt[b], 1.0f);
  for (int i = threadIdx.x; i < 256; i += 128) p[i] = pooled[b * 256 + i] * inv;
  __syncthreads();
  for (int j = threadIdx.x; j < 100; j += 128) {
    float s = b1[j];
    for (int k = 0; k < 256; ++k) s += p[k] * w1[k * 100 + j];
    h1[j] = fmaxf(s, 0.f);
  }
  __syncthreads();
  if (threadIdx.x < 10) {
    int j = threadIdx.x;
    float s = b2[j];
    for (int k = 0; k < 100; ++k) s += h1[k] * w2[k * 10 + j];
    lo[j] = s;
  }
  __syncthreads();
  if (threadIdx.x == 0) {
    float m = lo[0];
    for (int j = 1; j < 10; ++j) m = fmaxf(m, lo[j]);
    float ssum = 0.f;
    for (int j = 0; j < 10; ++j) ssum += expf(lo[j] - m);
    float lse = m + logf(ssum);
    for (int j = 0; j < 10; ++j) out[b * 10 + j] = lo[j] - lse;
  }
}

extern "C" void kernel_launch(void* const* d_in, const int* in_sizes, int n_in,
                              void* d_out, int out_size, void* d_ws, size_t ws_size,
                              hipStream_t stream) {
  const float* x     = (const float*)d_in[0];
  const int*   ei    = (const int*)d_in[1];
  const int*   batch = (const int*)d_in[2];
  const float* W1 = (const float*)d_in[3];  const float* b1 = (const float*)d_in[4];
  const float* W2 = (const float*)d_in[5];  const float* b2 = (const float*)d_in[6];
  const float* W3 = (const float*)d_in[7];  const float* b3 = (const float*)d_in[8];
  const float* W4 = (const float*)d_in[9];  const float* b4 = (const float*)d_in[10];
  const float* fc1w = (const float*)d_in[11]; const float* fc1b = (const float*)d_in[12];
  const float* fc2w = (const float*)d_in[13]; const float* fc2b = (const float*)d_in[14];
  float* out = (float*)d_out;

  const int* src = ei;
  const int* dst = ei + NE;

  // ---- workspace layout ----
  float* ws = (float*)d_ws;
  float* dinv   = ws;                      // 100352
  float* R5     = dinv + 100352;           // 500480
  float* pooled = R5 + 500480;             // 16384
  float* pcnt   = pooled + 16384;          // 64
  int*   cnt       = (int*)(pcnt + 64);    // 100352
  int*   excl      = cnt + 100352;         // 100352
  int*   partial   = excl + 100352;        // 256
  int*   rowptr    = partial + 256;        // 100352
  int*   bucketCnt = rowptr + 100352;      // 512
  int*   bucketBase= bucketCnt + 512;      // 512
  int*   bucketPos = bucketBase + 512;     // 512
  int*   csrc      = bucketPos + 512;      // NE
  uint2* pairs     = (uint2*)(csrc + NE);  // NE uint2 (aligned: offset even)
  unsigned short* F0  = (unsigned short*)(pairs + NE);  // NN*32
  unsigned short* F1  = F0 + (size_t)NN * 32;           // NN*64
  unsigned short* F2  = F1 + (size_t)NN * 64;           // NN*128
  unsigned short* F3  = F2 + (size_t)NN * 128;          // NN*256
  unsigned short* AG  = F3 + (size_t)NN * 256;          // NN*128
  unsigned short* Wt2 = AG + (size_t)NN * 128;          // 32*64
  unsigned short* Wt3 = Wt2 + 32 * 64;                  // 64*128
  unsigned short* Wt4 = Wt3 + 64 * 128;                 // 128*256

  // ---- CSR build: hist -> bscan -> bin -> cnt/dinv -> scan -> local fill ----
  hipMemsetAsync(bucketCnt, 0, 512 * sizeof(int), stream);
  k_hist<<<(NE + 4095) / 4096, 256, 0, stream>>>(dst, bucketCnt);
  k_bscan<<<1, 512, 0, stream>>>(bucketCnt, bucketBase, bucketPos);
  k_bin<<<(NE + 4095) / 4096, 256, 0, stream>>>(src, dst, bucketPos, pairs);
  k_cnt<<<NB, 256, 0, stream>>>(pairs, bucketBase, bucketPos, cnt, dinv);
  k_scan1<<<196, 512, 0, stream>>>(cnt, excl, partial);
  k_scan2<<<1, 256, 0, stream>>>(partial);
  k_scan3<<<196, 512, 0, stream>>>(excl, partial, rowptr);
  k_fill_local<<<NB, 256, 0, stream>>>(pairs, bucketBase, bucketPos, rowptr, csrc);

  // ---- weight transposes ----
  k_wt<<<(32 * 64 + 255) / 256, 256, 0, stream>>>(W2, Wt2, 32, 64);
  k_wt<<<(64 * 128 + 255) / 256, 256, 0, stream>>>(W3, Wt3, 64, 128);
  k_wt<<<(128 * 256 + 255) / 256, 256, 0, stream>>>(W4, Wt4, 128, 256);

  // ---- layer 1: gather x (K=5) fp32, GEMM 5->32, bf16 out ----
  k_gather5<<<3125, 256, 0, stream>>>(x, rowptr, csrc, dinv, R5);
  k_gemm1<<<(NN + 255) / 256, 256, 0, stream>>>(R5, W1, b1, F0);

  // ---- layer 2: K=32 -> M=64 ----
  k_gatherb<32><<<(NN + 63) / 64, 256, 0, stream>>>(F0, rowptr, csrc, dinv, AG);
  k_gemm_mfma<32, 64><<<(NN + 63) / 64, 256, 0, stream>>>(AG, Wt2, b2, F1);

  // ---- layer 3: K=64 -> M=128 ----
  k_gatherb<64><<<(NN + 31) / 32, 256, 0, stream>>>(F1, rowptr, csrc, dinv, AG);
  k_gemm_mfma<64, 128><<<(NN + 63) / 64, 256, 0, stream>>>(AG, Wt3, b3, F2);

  // ---- layer 4: K=128 -> M=256 ----
  k_gatherb<128><<<(NN + 15) / 16, 256, 0, stream>>>(F2, rowptr, csrc, dinv, AG);
  k_gemm_mfma<128, 256><<<(NN + 63) / 64, 256, 0, stream>>>(AG, Wt4, b4, F3);

  // ---- mean pool + MLP head ----
  hipMemsetAsync(pooled, 0, (16384 + 64) * sizeof(float), stream);
  k_pool<<<(NN + 127) / 128, 256, 0, stream>>>(F3, batch, pooled, pcnt);
  k_mlp<<<NBATCH, 128, 0, stream>>>(pooled, pcnt, fc1w, fc1b, fc2w, fc2b, out);
}

// Round 5
// 411.373 us; speedup vs baseline: 5.2702x; 1.0323x over previous
//
#include <hip/hip_runtime.h>
#include <hip/hip_bf16.h>
#include <cmath>

#define NN 100000
#define NE 1600000
#define NBATCH 64
#define NB 391      // buckets of 256 nodes (dst>>8)
#define NBP 512     // padded bucket count

typedef __attribute__((ext_vector_type(8))) short bf16x8;
typedef __attribute__((ext_vector_type(4))) float f32x4;

__device__ __forceinline__ void atomAdd(float* p, float v) {
  unsafeAtomicAdd(p, v);
}

__device__ __forceinline__ unsigned short f2bf(float f) {
  __hip_bfloat16 h = __float2bfloat16(f);
  union { __hip_bfloat16 h; unsigned short u; } cv; cv.h = h; return cv.u;
}
__device__ __forceinline__ float bflo(unsigned int u) { return __uint_as_float(u << 16); }
__device__ __forceinline__ float bfhi(unsigned int u) { return __uint_as_float(u & 0xffff0000u); }

// ---------------- bucket histogram (LDS-staged) ----------------
__global__ __launch_bounds__(256) void k_hist(const int* __restrict__ dst,
    int* __restrict__ bucketCnt) {
  __shared__ int h[NBP];
  for (int i = threadIdx.x; i < NBP; i += 256) h[i] = 0;
  __syncthreads();
  const int base = blockIdx.x * 4096;
  const int n = (NE - base < 4096) ? NE - base : 4096;
  for (int i = threadIdx.x; i < n; i += 256) atomicAdd(&h[dst[base + i] >> 8], 1);
  __syncthreads();
  for (int i = threadIdx.x; i < NB; i += 256)
    if (h[i]) atomicAdd(&bucketCnt[i], h[i]);
}

// ---------------- bucket base scan (1 block) ----------------
__global__ __launch_bounds__(512) void k_bscan(const int* __restrict__ bucketCnt,
    int* __restrict__ bucketBase, int* __restrict__ bucketPos) {
  __shared__ int s[NBP];
  int v = (threadIdx.x < NB) ? bucketCnt[threadIdx.x] : 0;
  s[threadIdx.x] = v;
  __syncthreads();
  for (int off = 1; off < NBP; off <<= 1) {
    int t = (threadIdx.x >= (unsigned)off) ? s[threadIdx.x - off] : 0;
    __syncthreads();
    s[threadIdx.x] += t;
    __syncthreads();
  }
  if (threadIdx.x < NB) {
    int ex = s[threadIdx.x] - v;
    bucketBase[threadIdx.x] = ex;
    bucketPos[threadIdx.x] = ex;
  }
}

// ---------------- bin edges into bucket regions (LDS counting sort per 4096-chunk) ----------------
__global__ __launch_bounds__(256) void k_bin(const int* __restrict__ src,
    const int* __restrict__ dst, int* __restrict__ bucketPos, uint2* __restrict__ pairs) {
  __shared__ int hist[NBP];
  __shared__ int scn[NBP];
  __shared__ int ofs[NBP];
  __shared__ int gbase[NBP];
  __shared__ uint2 buf[4096];
  const int base = blockIdx.x * 4096;
  const int n = (NE - base < 4096) ? NE - base : 4096;
  for (int i = threadIdx.x; i < NBP; i += 256) hist[i] = 0;
  __syncthreads();

  int myS[16], myD[16];
  int nloc = 0;
  for (int i = threadIdx.x, j = 0; i < n; i += 256, ++j) {
    myS[j] = src[base + i];
    myD[j] = dst[base + i];
    atomicAdd(&hist[myD[j] >> 8], 1);
    nloc = j + 1;
  }
  __syncthreads();

  scn[threadIdx.x] = hist[threadIdx.x];
  scn[threadIdx.x + 256] = hist[threadIdx.x + 256];
  __syncthreads();
  for (int off = 1; off < NBP; off <<= 1) {
    const int i0 = threadIdx.x, i1 = threadIdx.x + 256;
    int t0 = (i0 >= off) ? scn[i0 - off] : 0;
    int t1 = (i1 >= off) ? scn[i1 - off] : 0;
    __syncthreads();
    scn[i0] += t0;
    scn[i1] += t1;
    __syncthreads();
  }
  ofs[threadIdx.x] = scn[threadIdx.x] - hist[threadIdx.x];
  ofs[threadIdx.x + 256] = scn[threadIdx.x + 256] - hist[threadIdx.x + 256];
  for (int b = threadIdx.x; b < NB; b += 256) {
    int c = hist[b];
    if (c) gbase[b] = atomicAdd(&bucketPos[b], c);
  }
  __syncthreads();

  for (int j = 0; j < nloc; ++j) {
    int b = myD[j] >> 8;
    int slot = atomicAdd(&ofs[b], 1);
    buf[slot] = make_uint2((unsigned)myS[j], (unsigned)myD[j]);
  }
  __syncthreads();

  for (int i = threadIdx.x; i < n; i += 256) {
    uint2 p = buf[i];
    int b = (int)(p.y >> 8);
    int ex = scn[b] - hist[b];
    pairs[gbase[b] + (i - ex)] = p;
  }
}

// ---------------- per-bucket degree count + dinv (LDS counters) ----------------
__global__ __launch_bounds__(256) void k_cnt(const uint2* __restrict__ pairs,
    const int* __restrict__ bucketBase, const int* __restrict__ bucketPos,
    int* __restrict__ cnt, float* __restrict__ dinv) {
  __shared__ int c[256];
  c[threadIdx.x] = 0;
  __syncthreads();
  const int b = blockIdx.x;
  const int s = bucketBase[b], e = bucketPos[b];
  for (int i = s + threadIdx.x; i < e; i += 256)
    atomicAdd(&c[pairs[i].y & 255], 1);
  __syncthreads();
  const int node = b * 256 + threadIdx.x;
  if (node < NN) {
    cnt[node] = c[threadIdx.x];
    dinv[node] = rsqrtf((float)c[threadIdx.x] + 1.0f);
  }
}

// ---------------- exclusive scan over nodes (3 kernels) ----------------
__global__ __launch_bounds__(512) void k_scan1(const int* __restrict__ cnt,
    int* __restrict__ excl, int* __restrict__ partial) {
  __shared__ int sh[512];
  int i = blockIdx.x * 512 + threadIdx.x;
  int v = (i < NN) ? cnt[i] : 0;
  sh[threadIdx.x] = v;
  __syncthreads();
  for (int off = 1; off < 512; off <<= 1) {
    int t = (threadIdx.x >= (unsigned)off) ? sh[threadIdx.x - off] : 0;
    __syncthreads();
    sh[threadIdx.x] += t;
    __syncthreads();
  }
  if (i < NN) excl[i] = sh[threadIdx.x] - v;
  if (threadIdx.x == 511) partial[blockIdx.x] = sh[511];
}

__global__ __launch_bounds__(256) void k_scan2(int* __restrict__ partial) {
  __shared__ int sh[256];
  int v = (threadIdx.x < 196) ? partial[threadIdx.x] : 0;
  sh[threadIdx.x] = v;
  __syncthreads();
  for (int off = 1; off < 256; off <<= 1) {
    int t = (threadIdx.x >= (unsigned)off) ? sh[threadIdx.x - off] : 0;
    __syncthreads();
    sh[threadIdx.x] += t;
    __syncthreads();
  }
  if (threadIdx.x < 196) partial[threadIdx.x] = sh[threadIdx.x] - v;
}

__global__ __launch_bounds__(512) void k_scan3(const int* __restrict__ excl,
    const int* __restrict__ partial, int* __restrict__ rowptr) {
  int i = blockIdx.x * 512 + threadIdx.x;
  if (i < NN) rowptr[i] = excl[i] + partial[blockIdx.x];
  if (i == NN) rowptr[NN] = NE;
}

// ---------------- bucket-local CSR fill (L2-local scatter) ----------------
__global__ __launch_bounds__(256) void k_fill_local(const uint2* __restrict__ pairs,
    const int* __restrict__ bucketBase, const int* __restrict__ bucketPos,
    const int* __restrict__ rowptr, int* __restrict__ csrc) {
  __shared__ int ofs[256];
  ofs[threadIdx.x] = 0;
  __syncthreads();
  const int b = blockIdx.x;
  const int s = bucketBase[b], e = bucketPos[b];
  for (int i = s + threadIdx.x; i < e; i += 256) {
    uint2 p = pairs[i];
    int d = (int)p.y;
    int pos = rowptr[d] + atomicAdd(&ofs[d & 255], 1);
    csrc[pos] = (int)p.x;
  }
}

// ---------------- batch counts ----------------
__global__ __launch_bounds__(256) void k_bcnt(const int* __restrict__ batch,
    float* __restrict__ pcnt) {
  __shared__ int h[64];
  if (threadIdx.x < 64) h[threadIdx.x] = 0;
  __syncthreads();
  int i = blockIdx.x * 256 + threadIdx.x;
  if (i < NN) atomicAdd(&h[batch[i]], 1);
  __syncthreads();
  if (threadIdx.x < 64 && h[threadIdx.x]) atomAdd(&pcnt[threadIdx.x], (float)h[threadIdx.x]);
}

// ---------------- weight convert + transpose: W[K][M] fp32 -> Wt[M][K] bf16 ----------------
__global__ __launch_bounds__(256) void k_wt(const float* __restrict__ W,
    unsigned short* __restrict__ Wt, int K, int M) {
  int idx = blockIdx.x * 256 + threadIdx.x;
  if (idx < K * M) {
    int k = idx / M, m = idx - k * M;
    Wt[m * K + k] = f2bf(W[idx]);
  }
}

// ---------------- layer 1 fused: gather(K=5,fp32) + GEMM 5->32 + ReLU, bf16 out ----------------
__global__ __launch_bounds__(256) void k_l1(const float* __restrict__ x,
    const int* __restrict__ rowptr, const int* __restrict__ csrc,
    const float* __restrict__ dinv, const float* __restrict__ W,
    const float* __restrict__ b, unsigned short* __restrict__ outp) {
  __shared__ float xs[32][6];
  const int lr = threadIdx.x / 8;
  const int k = threadIdx.x % 8;
  const int r = blockIdx.x * 32 + lr;
  if (r < NN && k < 5) {
    const float di = dinv[r];
    float acc = x[(size_t)r * 5 + k] * di * di;
    const int e1 = rowptr[r + 1];
    for (int e = rowptr[r]; e < e1; ++e) {
      const int s = csrc[e];
      acc += x[(size_t)s * 5 + k] * dinv[s] * di;
    }
    xs[lr][k] = acc;
  }
  __syncthreads();
  if (r >= NN) return;
  const float f0 = xs[lr][0], f1 = xs[lr][1], f2 = xs[lr][2], f3 = xs[lr][3], f4 = xs[lr][4];
  unsigned int o[2];
#pragma unroll
  for (int j2 = 0; j2 < 2; ++j2) {
    const int c0 = k * 4 + j2 * 2;
    float s0 = b[c0]     + f0 * W[c0]     + f1 * W[32 + c0]     + f2 * W[64 + c0]     + f3 * W[96 + c0]     + f4 * W[128 + c0];
    float s1 = b[c0 + 1] + f0 * W[c0 + 1] + f1 * W[32 + c0 + 1] + f2 * W[64 + c0 + 1] + f3 * W[96 + c0 + 1] + f4 * W[128 + c0 + 1];
    s0 = fmaxf(s0, 0.f); s1 = fmaxf(s1, 0.f);
    o[j2] = (unsigned int)f2bf(s0) | ((unsigned int)f2bf(s1) << 16);
  }
  *(uint2*)(outp + (size_t)r * 32 + k * 4) = make_uint2(o[0], o[1]);
}

// ---------------- fused gather + MFMA GEMM (+ optional fused mean-pool) ----------------
// Block: 256 threads = 4 waves; 64 rows x M cols.
template<int K, int M, bool POOL>
__global__ __launch_bounds__(256) void k_fused(const unsigned short* __restrict__ in,
    const int* __restrict__ rowptr, const int* __restrict__ csrc,
    const float* __restrict__ dinv,
    const unsigned short* __restrict__ Wt, const float* __restrict__ bias,
    unsigned short* __restrict__ outp,
    const int* __restrict__ batch, float* __restrict__ pooled) {
  constexpr int KP = K + 8;
  constexpr int KC = 32;
  constexpr int WP = KC + 8;
  constexpr int CTW = M / 64;
  constexpr int TPR = K / 8;       // lanes per row in gather phase
  constexpr int RPB = 256 / TPR;   // rows per gather pass
  __shared__ unsigned short a_s[64 * KP];
  __shared__ unsigned short w_s[M * WP];
  const int r0 = blockIdx.x * 64;
  const int tid = threadIdx.x;

  // ---- phase 1: gather agg rows directly into LDS ----
  {
    const int lrow = tid / TPR;
    const int c = (tid % TPR) * 8;
#pragma unroll
    for (int rp = 0; rp < 64; rp += RPB) {
      const int r = r0 + rp + lrow;
      uint4 o = {0u, 0u, 0u, 0u};
      if (r < NN) {
        const float di = dinv[r];
        const float sl = di * di;
        float a0[8], a1[8];
        const uint4 v = *(const uint4*)(in + (size_t)r * K + c);
        a0[0] = bflo(v.x) * sl; a0[1] = bfhi(v.x) * sl;
        a0[2] = bflo(v.y) * sl; a0[3] = bfhi(v.y) * sl;
        a0[4] = bflo(v.z) * sl; a0[5] = bfhi(v.z) * sl;
        a0[6] = bflo(v.w) * sl; a0[7] = bfhi(v.w) * sl;
#pragma unroll
        for (int j = 0; j < 8; ++j) a1[j] = 0.f;
        int e = rowptr[r];
        const int e1 = rowptr[r + 1];
        for (; e + 2 <= e1; e += 2) {
          const int s0 = csrc[e], s1 = csrc[e + 1];
          const float w0 = dinv[s0] * di, w1 = dinv[s1] * di;
          const uint4 v0 = *(const uint4*)(in + (size_t)s0 * K + c);
          const uint4 v1 = *(const uint4*)(in + (size_t)s1 * K + c);
          a0[0] += bflo(v0.x) * w0; a0[1] += bfhi(v0.x) * w0;
          a0[2] += bflo(v0.y) * w0; a0[3] += bfhi(v0.y) * w0;
          a0[4] += bflo(v0.z) * w0; a0[5] += bfhi(v0.z) * w0;
          a0[6] += bflo(v0.w) * w0; a0[7] += bfhi(v0.w) * w0;
          a1[0] += bflo(v1.x) * w1; a1[1] += bfhi(v1.x) * w1;
          a1[2] += bflo(v1.y) * w1; a1[3] += bfhi(v1.y) * w1;
          a1[4] += bflo(v1.z) * w1; a1[5] += bfhi(v1.z) * w1;
          a1[6] += bflo(v1.w) * w1; a1[7] += bfhi(v1.w) * w1;
        }
        if (e < e1) {
          const int s0 = csrc[e];
          const float w0 = dinv[s0] * di;
          const uint4 v0 = *(const uint4*)(in + (size_t)s0 * K + c);
          a0[0] += bflo(v0.x) * w0; a0[1] += bfhi(v0.x) * w0;
          a0[2] += bflo(v0.y) * w0; a0[3] += bfhi(v0.y) * w0;
          a0[4] += bflo(v0.z) * w0; a0[5] += bfhi(v0.z) * w0;
          a0[6] += bflo(v0.w) * w0; a0[7] += bfhi(v0.w) * w0;
        }
        o.x = (unsigned int)f2bf(a0[0] + a1[0]) | ((unsigned int)f2bf(a0[1] + a1[1]) << 16);
        o.y = (unsigned int)f2bf(a0[2] + a1[2]) | ((unsigned int)f2bf(a0[3] + a1[3]) << 16);
        o.z = (unsigned int)f2bf(a0[4] + a1[4]) | ((unsigned int)f2bf(a0[5] + a1[5]) << 16);
        o.w = (unsigned int)f2bf(a0[6] + a1[6]) | ((unsigned int)f2bf(a0[7] + a1[7]) << 16);
      }
      *(uint4*)&a_s[(rp + lrow) * KP + c] = o;
    }
  }

  // ---- phase 2: MFMA ----
  const int wave = tid >> 6, lane = tid & 63;
  const int m16 = lane & 15, q = lane >> 4;
  f32x4 acc[4][CTW];
#pragma unroll
  for (int rt = 0; rt < 4; ++rt)
#pragma unroll
    for (int ct = 0; ct < CTW; ++ct) acc[rt][ct] = (f32x4){0.f, 0.f, 0.f, 0.f};

  for (int kc = 0; kc < K; kc += KC) {
    __syncthreads();
    for (int idx = tid; idx < M * (KC / 8); idx += 256) {
      int m = idx / (KC / 8), cc = (idx % (KC / 8)) * 8;
      uint4 v = *(const uint4*)(Wt + (size_t)m * K + kc + cc);
      *(uint4*)&w_s[m * WP + cc] = v;
    }
    __syncthreads();
    bf16x8 bfr[CTW];
#pragma unroll
    for (int ct = 0; ct < CTW; ++ct)
      bfr[ct] = *(const bf16x8*)&w_s[(wave * (M / 4) + ct * 16 + m16) * WP + q * 8];
#pragma unroll
    for (int rt = 0; rt < 4; ++rt) {
      bf16x8 afr = *(const bf16x8*)&a_s[(rt * 16 + m16) * KP + kc + q * 8];
#pragma unroll
      for (int ct = 0; ct < CTW; ++ct)
        acc[rt][ct] = __builtin_amdgcn_mfma_f32_16x16x32_bf16(afr, bfr[ct], acc[rt][ct], 0, 0, 0);
    }
  }

  // ---- epilogue ----
  if constexpr (POOL) {
    // segmented mean-pool: block rows span >=1 consecutive batch ids (batch sorted)
    const int rlast = (r0 + 63 < NN) ? r0 + 63 : NN - 1;
    const int bmin = batch[r0];
    const int bmax = batch[rlast];
    int rowb[4][4];
#pragma unroll
    for (int rt = 0; rt < 4; ++rt)
#pragma unroll
      for (int reg = 0; reg < 4; ++reg) {
        const int row = r0 + rt * 16 + q * 4 + reg;
        rowb[rt][reg] = (row < NN) ? batch[row] : -1;
      }
#pragma unroll
    for (int ct = 0; ct < CTW; ++ct) {
      const int col = wave * (M / 4) + ct * 16 + m16;
      const float bv = bias[col];
      for (int b = bmin; b <= bmax; ++b) {
        float s = 0.f;
#pragma unroll
        for (int rt = 0; rt < 4; ++rt)
#pragma unroll
          for (int reg = 0; reg < 4; ++reg)
            if (rowb[rt][reg] == b) s += fmaxf(acc[rt][ct][reg] + bv, 0.f);
        s += __shfl_xor(s, 16);
        s += __shfl_xor(s, 32);
        if (q == 0) atomAdd(&pooled[b * M + col], s);
      }
    }
  } else {
#pragma unroll
    for (int rt = 0; rt < 4; ++rt) {
#pragma unroll
      for (int ct = 0; ct < CTW; ++ct) {
        const int col = wave * (M / 4) + ct * 16 + m16;
        const float bv = bias[col];
#pragma unroll
        for (int reg = 0; reg < 4; ++reg) {
          const int row = r0 + rt * 16 + q * 4 + reg;
          if (row < NN) {
            float vv = fmaxf(acc[rt][ct][reg] + bv, 0.f);
            outp[(size_t)row * M + col] = f2bf(vv);
          }
        }
      }
    }
  }
}

// ---------------- MLP head + log_softmax ----------------
__global__ __launch_bounds__(128) void k_mlp(const float* __restrict__ pooled,
    const float* __restrict__ cnt, const float* __restrict__ w1,
    const float* __restrict__ b1, const float* __restrict__ w2,
    const float* __restrict__ b2, float* __restrict__ out) {
  __shared__ float p[256];
  __shared__ float h1[100];
  __shared__ float lo[10];
  const int b = blockIdx.x;
  const float inv = 1.0f / fmaxf(cnt[b], 1.0f);
  for (int i = threadIdx.x; i < 256; i += 128) p[i] = pooled[b * 256 + i] * inv;
  __syncthreads();
  for (int j = threadIdx.x; j < 100; j += 128) {
    float s = b1[j];
    for (int k = 0; k < 256; ++k) s += p[k] * w1[k * 100 + j];
    h1[j] = fmaxf(s, 0.f);
  }
  __syncthreads();
  if (threadIdx.x < 10) {
    int j = threadIdx.x;
    float s = b2[j];
    for (int k = 0; k < 100; ++k) s += h1[k] * w2[k * 10 + j];
    lo[j] = s;
  }
  __syncthreads();
  if (threadIdx.x == 0) {
    float m = lo[0];
    for (int j = 1; j < 10; ++j) m = fmaxf(m, lo[j]);
    float ssum = 0.f;
    for (int j = 0; j < 10; ++j) ssum += expf(lo[j] - m);
    float lse = m + logf(ssum);
    for (int j = 0; j < 10; ++j) out[b * 10 + j] = lo[j] - lse;
  }
}

extern "C" void kernel_launch(void* const* d_in, const int* in_sizes, int n_in,
                              void* d_out, int out_size, void* d_ws, size_t ws_size,
                              hipStream_t stream) {
  const float* x     = (const float*)d_in[0];
  const int*   ei    = (const int*)d_in[1];
  const int*   batch = (const int*)d_in[2];
  const float* W1 = (const float*)d_in[3];  const float* b1 = (const float*)d_in[4];
  const float* W2 = (const float*)d_in[5];  const float* b2 = (const float*)d_in[6];
  const float* W3 = (const float*)d_in[7];  const float* b3 = (const float*)d_in[8];
  const float* W4 = (const float*)d_in[9];  const float* b4 = (const float*)d_in[10];
  const float* fc1w = (const float*)d_in[11]; const float* fc1b = (const float*)d_in[12];
  const float* fc2w = (const float*)d_in[13]; const float* fc2b = (const float*)d_in[14];
  float* out = (float*)d_out;

  const int* src = ei;
  const int* dst = ei + NE;

  // ---- workspace layout ----
  float* ws = (float*)d_ws;
  float* dinv   = ws;                      // 100352
  float* pooled = dinv + 100352;           // 16384
  float* pcnt   = pooled + 16384;          // 64
  int*   cnt       = (int*)(pcnt + 64);    // 100352
  int*   excl      = cnt + 100352;         // 100352
  int*   partial   = excl + 100352;        // 256
  int*   rowptr    = partial + 256;        // 100352
  int*   bucketCnt = rowptr + 100352;      // 512
  int*   bucketBase= bucketCnt + 512;      // 512
  int*   bucketPos = bucketBase + 512;     // 512
  int*   csrc      = bucketPos + 512;      // NE
  uint2* pairs     = (uint2*)(csrc + NE);  // NE uint2
  unsigned short* F0  = (unsigned short*)(pairs + NE);  // NN*32
  unsigned short* F1  = F0 + (size_t)NN * 32;           // NN*64
  unsigned short* F2  = F1 + (size_t)NN * 64;           // NN*128
  unsigned short* Wt2 = F2 + (size_t)NN * 128;          // 32*64
  unsigned short* Wt3 = Wt2 + 32 * 64;                  // 64*128
  unsigned short* Wt4 = Wt3 + 64 * 128;                 // 128*256

  // ---- CSR build ----
  hipMemsetAsync(bucketCnt, 0, 512 * sizeof(int), stream);
  k_hist<<<(NE + 4095) / 4096, 256, 0, stream>>>(dst, bucketCnt);
  k_bscan<<<1, 512, 0, stream>>>(bucketCnt, bucketBase, bucketPos);
  k_bin<<<(NE + 4095) / 4096, 256, 0, stream>>>(src, dst, bucketPos, pairs);
  k_cnt<<<NB, 256, 0, stream>>>(pairs, bucketBase, bucketPos, cnt, dinv);
  k_scan1<<<196, 512, 0, stream>>>(cnt, excl, partial);
  k_scan2<<<1, 256, 0, stream>>>(partial);
  k_scan3<<<196, 512, 0, stream>>>(excl, partial, rowptr);
  k_fill_local<<<NB, 256, 0, stream>>>(pairs, bucketBase, bucketPos, rowptr, csrc);

  // ---- weights + batch counts + pooled init ----
  k_wt<<<(32 * 64 + 255) / 256, 256, 0, stream>>>(W2, Wt2, 32, 64);
  k_wt<<<(64 * 128 + 255) / 256, 256, 0, stream>>>(W3, Wt3, 64, 128);
  k_wt<<<(128 * 256 + 255) / 256, 256, 0, stream>>>(W4, Wt4, 128, 256);
  hipMemsetAsync(pooled, 0, (16384 + 64) * sizeof(float), stream);
  k_bcnt<<<(NN + 255) / 256, 256, 0, stream>>>(batch, pcnt);

  // ---- layers ----
  k_l1<<<3125, 256, 0, stream>>>(x, rowptr, csrc, dinv, W1, b1, F0);
  k_fused<32, 64, false><<<(NN + 63) / 64, 256, 0, stream>>>(
      F0, rowptr, csrc, dinv, Wt2, b2, F1, nullptr, nullptr);
  k_fused<64, 128, false><<<(NN + 63) / 64, 256, 0, stream>>>(
      F1, rowptr, csrc, dinv, Wt3, b3, F2, nullptr, nullptr);
  k_fused<128, 256, true><<<(NN + 63) / 64, 256, 0, stream>>>(
      F2, rowptr, csrc, dinv, Wt4, b4, nullptr, batch, pooled);

  // ---- MLP head ----
  k_mlp<<<NBATCH, 128, 0, stream>>>(pooled, pcnt, fc1w, fc1b, fc2w, fc2b, out);
}